// Round 6
// baseline (6978.185 us; speedup 1.0000x reference)
//
#include <hip/hip_runtime.h>
#include <cmath>

#define DEV __device__ __forceinline__

constexpr float LN_EPS = 1e-5f;

DEV float gelu_f(float x) { return 0.5f * x * (1.f + erff(x * 0.70710678118654752440f)); }
DEV float sigmoid_f(float x) { return 1.f / (1.f + __expf(-x)); }

DEV float wred_sum(float v) {
#pragma unroll
  for (int m = 1; m < 64; m <<= 1) v += __shfl_xor(v, m, 64);
  return v;
}

// r = (b*128 + t)*64 + c  ->  (b*64 + c)*128 + t
DEV int permrow_btc_to_bct(int r) {
  int bI = r >> 13, t = (r >> 6) & 127, cI = r & 63;
  return ((((bI << 6) | cI) << 7) | t);
}

// ---------------------------------------------------------------------------
// Generic GEMM: C[r,o] = act(sum_k A[r,k]*W[o,k] + bias[o])
// rows multiple of 128, M multiple of 64, K multiple of 16.
// ---------------------------------------------------------------------------
template <int ACT>  // 0 none, 1 gelu
__global__ __launch_bounds__(256, 2) void gemm_k(const float* __restrict__ A,
                                                 const float* __restrict__ W,
                                                 const float* __restrict__ bias,
                                                 float* __restrict__ Cout, int K, int M) {
  __shared__ float As[16][132];
  __shared__ float Ws[16][68];
  const int tid = threadIdx.x;
  const int row0 = blockIdx.y << 7;
  const int col0 = blockIdx.x << 6;
  const int lm = tid >> 2;
  const int lk = (tid & 3) << 2;
  const int mi = (tid >> 4) << 3;
  const int ni = (tid & 15) << 2;
  float acc[8][4];
#pragma unroll
  for (int i = 0; i < 8; ++i)
#pragma unroll
    for (int j = 0; j < 4; ++j) acc[i][j] = 0.f;
  for (int k0 = 0; k0 < K; k0 += 16) {
    float4 a0 = *(const float4*)&A[(size_t)(row0 + lm) * K + k0 + lk];
    float4 a1 = *(const float4*)&A[(size_t)(row0 + 64 + lm) * K + k0 + lk];
    float4 w0 = *(const float4*)&W[(size_t)(col0 + lm) * K + k0 + lk];
    __syncthreads();
    As[lk + 0][lm] = a0.x; As[lk + 1][lm] = a0.y; As[lk + 2][lm] = a0.z; As[lk + 3][lm] = a0.w;
    As[lk + 0][64 + lm] = a1.x; As[lk + 1][64 + lm] = a1.y; As[lk + 2][64 + lm] = a1.z; As[lk + 3][64 + lm] = a1.w;
    Ws[lk + 0][lm] = w0.x; Ws[lk + 1][lm] = w0.y; Ws[lk + 2][lm] = w0.z; Ws[lk + 3][lm] = w0.w;
    __syncthreads();
#pragma unroll
    for (int k = 0; k < 16; ++k) {
      float4 av0 = *(const float4*)&As[k][mi];
      float4 av1 = *(const float4*)&As[k][mi + 4];
      float4 wv = *(const float4*)&Ws[k][ni];
      float am[8] = {av0.x, av0.y, av0.z, av0.w, av1.x, av1.y, av1.z, av1.w};
      float wn[4] = {wv.x, wv.y, wv.z, wv.w};
#pragma unroll
      for (int i = 0; i < 8; ++i)
#pragma unroll
        for (int j = 0; j < 4; ++j) acc[i][j] = fmaf(am[i], wn[j], acc[i][j]);
    }
  }
  float4 bv = *(const float4*)&bias[col0 + ni];
#pragma unroll
  for (int i = 0; i < 8; ++i) {
    float4 o;
    o.x = acc[i][0] + bv.x; o.y = acc[i][1] + bv.y;
    o.z = acc[i][2] + bv.z; o.w = acc[i][3] + bv.w;
    if (ACT == 1) { o.x = gelu_f(o.x); o.y = gelu_f(o.y); o.z = gelu_f(o.z); o.w = gelu_f(o.w); }
    *(float4*)&Cout[(size_t)(row0 + mi + i) * M + col0 + ni] = o;
  }
}

// ---------------------------------------------------------------------------
// Gate: out[r,o] = y*g + res*(1-g), g = sigmoid([y,res] @ W^T + b). K=512, M=256.
// PERM: y is stored in (b,c,t) row order while r is (b,t,c).
// ---------------------------------------------------------------------------
template <bool PERM>
__global__ __launch_bounds__(256, 2) void gate_k(const float* __restrict__ Y,
                                                 const float* __restrict__ R,
                                                 const float* __restrict__ W,
                                                 const float* __restrict__ bias,
                                                 float* __restrict__ Out) {
  __shared__ float As[16][132];
  __shared__ float Ws[16][68];
  const int tid = threadIdx.x;
  const int row0 = blockIdx.y << 7;
  const int col0 = blockIdx.x << 6;
  const int lm = tid >> 2;
  const int lk = (tid & 3) << 2;
  const int mi = (tid >> 4) << 3;
  const int ni = (tid & 15) << 2;
  const int r1 = row0 + lm, r2 = r1 + 64;
  const int y1 = PERM ? permrow_btc_to_bct(r1) : r1;
  const int y2 = PERM ? permrow_btc_to_bct(r2) : r2;
  float acc[8][4];
#pragma unroll
  for (int i = 0; i < 8; ++i)
#pragma unroll
    for (int j = 0; j < 4; ++j) acc[i][j] = 0.f;
  for (int k0 = 0; k0 < 512; k0 += 16) {
    const float* p1;
    const float* p2;
    if (k0 < 256) {
      p1 = Y + (size_t)y1 * 256 + k0 + lk;
      p2 = Y + (size_t)y2 * 256 + k0 + lk;
    } else {
      p1 = R + (size_t)r1 * 256 + (k0 - 256) + lk;
      p2 = R + (size_t)r2 * 256 + (k0 - 256) + lk;
    }
    float4 a0 = *(const float4*)p1;
    float4 a1 = *(const float4*)p2;
    float4 w0 = *(const float4*)&W[(size_t)(col0 + lm) * 512 + k0 + lk];
    __syncthreads();
    As[lk + 0][lm] = a0.x; As[lk + 1][lm] = a0.y; As[lk + 2][lm] = a0.z; As[lk + 3][lm] = a0.w;
    As[lk + 0][64 + lm] = a1.x; As[lk + 1][64 + lm] = a1.y; As[lk + 2][64 + lm] = a1.z; As[lk + 3][64 + lm] = a1.w;
    Ws[lk + 0][lm] = w0.x; Ws[lk + 1][lm] = w0.y; Ws[lk + 2][lm] = w0.z; Ws[lk + 3][lm] = w0.w;
    __syncthreads();
#pragma unroll
    for (int k = 0; k < 16; ++k) {
      float4 av0 = *(const float4*)&As[k][mi];
      float4 av1 = *(const float4*)&As[k][mi + 4];
      float4 wv = *(const float4*)&Ws[k][ni];
      float am[8] = {av0.x, av0.y, av0.z, av0.w, av1.x, av1.y, av1.z, av1.w};
      float wn[4] = {wv.x, wv.y, wv.z, wv.w};
#pragma unroll
      for (int i = 0; i < 8; ++i)
#pragma unroll
        for (int j = 0; j < 4; ++j) acc[i][j] = fmaf(am[i], wn[j], acc[i][j]);
    }
  }
  float4 bv = *(const float4*)&bias[col0 + ni];
#pragma unroll
  for (int i = 0; i < 8; ++i) {
    int r = row0 + mi + i;
    int yr = PERM ? permrow_btc_to_bct(r) : r;
    float4 yv = *(const float4*)&Y[(size_t)yr * 256 + col0 + ni];
    float4 rv = *(const float4*)&R[(size_t)r * 256 + col0 + ni];
    float g0 = sigmoid_f(acc[i][0] + bv.x);
    float g1 = sigmoid_f(acc[i][1] + bv.y);
    float g2 = sigmoid_f(acc[i][2] + bv.z);
    float g3 = sigmoid_f(acc[i][3] + bv.w);
    float4 o;
    o.x = yv.x * g0 + rv.x * (1.f - g0);
    o.y = yv.y * g1 + rv.y * (1.f - g1);
    o.z = yv.z * g2 + rv.z * (1.f - g2);
    o.w = yv.w * g3 + rv.w * (1.f - g3);
    *(float4*)&Out[(size_t)r * 256 + col0 + ni] = o;
  }
}

// ---------------------------------------------------------------------------
// Conv-proj: co[r=(bc,t), o] = sum_{k<252} cat[bc,k,t] * W[o,k] + b[o]
// ---------------------------------------------------------------------------
__global__ __launch_bounds__(256, 2) void convproj_k(const float* __restrict__ catb,
                                                     const float* __restrict__ W,
                                                     const float* __restrict__ bias,
                                                     float* __restrict__ Co) {
  __shared__ float As[16][132];
  __shared__ float Ws[16][68];
  const int tid = threadIdx.x;
  const int row0 = blockIdx.y << 7;
  const int bc = row0 >> 7;
  const int col0 = blockIdx.x << 6;
  const int lm = tid >> 2;
  const int lk = (tid & 3) << 2;
  const int mi = (tid >> 4) << 3;
  const int ni = (tid & 15) << 2;
  float acc[8][4];
#pragma unroll
  for (int i = 0; i < 8; ++i)
#pragma unroll
    for (int j = 0; j < 4; ++j) acc[i][j] = 0.f;
  for (int k0 = 0; k0 < 252; k0 += 16) {
    float a_r[8];
#pragma unroll
    for (int it = 0; it < 8; ++it) {
      int idx = it * 256 + tid;
      int kk = idx >> 7, tl = idx & 127;
      a_r[it] = (k0 + kk < 252) ? catb[((size_t)bc * 252 + k0 + kk) * 128 + tl] : 0.f;
    }
    float4 w0;
    if (k0 + lk <= 248)
      w0 = *(const float4*)&W[(size_t)(col0 + lm) * 252 + k0 + lk];
    else
      w0 = float4{0.f, 0.f, 0.f, 0.f};
    __syncthreads();
#pragma unroll
    for (int it = 0; it < 8; ++it) {
      int idx = it * 256 + tid;
      As[idx >> 7][idx & 127] = a_r[it];
    }
    Ws[lk + 0][lm] = w0.x; Ws[lk + 1][lm] = w0.y; Ws[lk + 2][lm] = w0.z; Ws[lk + 3][lm] = w0.w;
    __syncthreads();
#pragma unroll
    for (int k = 0; k < 16; ++k) {
      float4 av0 = *(const float4*)&As[k][mi];
      float4 av1 = *(const float4*)&As[k][mi + 4];
      float4 wv = *(const float4*)&Ws[k][ni];
      float am[8] = {av0.x, av0.y, av0.z, av0.w, av1.x, av1.y, av1.z, av1.w};
      float wn[4] = {wv.x, wv.y, wv.z, wv.w};
#pragma unroll
      for (int i = 0; i < 8; ++i)
#pragma unroll
        for (int j = 0; j < 4; ++j) acc[i][j] = fmaf(am[i], wn[j], acc[i][j]);
    }
  }
  float4 bv = *(const float4*)&bias[col0 + ni];
#pragma unroll
  for (int i = 0; i < 8; ++i) {
    float4 o;
    o.x = acc[i][0] + bv.x; o.y = acc[i][1] + bv.y;
    o.z = acc[i][2] + bv.z; o.w = acc[i][3] + bv.w;
    *(float4*)&Co[(size_t)(row0 + mi + i) * 256 + col0 + ni] = o;
  }
}

// ---------------------------------------------------------------------------
// Attention (online softmax), one wave-lane per query row. L=64 (bias) or 128.
// qkv rows: [seq*L + l][768] with q|k|v each 256 = 8 heads * 32.
// ---------------------------------------------------------------------------
template <int L, bool HASB>
__global__ __launch_bounds__(L) void attn_k(const float* __restrict__ qkv,
                                            const float* __restrict__ bmat,
                                            float* __restrict__ Out) {
  __shared__ float Ks[L][34];
  __shared__ float Vs[L][34];
  __shared__ float Bs[HASB ? 64 * 65 : 1];
  const int s = blockIdx.x, h = blockIdx.y, l = threadIdx.x;
  const float* rowp = qkv + ((size_t)s * L + l) * 768 + h * 32;
  float q[32];
#pragma unroll
  for (int e = 0; e < 32; e += 4) {
    float4 t4 = *(const float4*)(rowp + e);
    q[e] = t4.x; q[e + 1] = t4.y; q[e + 2] = t4.z; q[e + 3] = t4.w;
    float4 k4 = *(const float4*)(rowp + 256 + e);
    Ks[l][e] = k4.x; Ks[l][e + 1] = k4.y; Ks[l][e + 2] = k4.z; Ks[l][e + 3] = k4.w;
    float4 v4 = *(const float4*)(rowp + 512 + e);
    Vs[l][e] = v4.x; Vs[l][e + 1] = v4.y; Vs[l][e + 2] = v4.z; Vs[l][e + 3] = v4.w;
  }
  if (HASB) {
#pragma unroll 1
    for (int j = 0; j < 64; ++j) Bs[l * 65 + j] = bmat[l * 64 + j];
  }
  __syncthreads();
  float m = -3.0e38f, den = 0.f;
  float acc[32];
#pragma unroll
  for (int e = 0; e < 32; ++e) acc[e] = 0.f;
  for (int kk = 0; kk < L; ++kk) {
    float sd = 0.f;
#pragma unroll
    for (int e = 0; e < 32; e += 2) {
      float2 kv = *(const float2*)&Ks[kk][e];
      sd = fmaf(q[e], kv.x, sd);
      sd = fmaf(q[e + 1], kv.y, sd);
    }
    float sc = sd * 0.17677669529663687f;
    if (HASB) sc += Bs[l * 65 + kk];
    float mn = fmaxf(m, sc);
    float corr = __expf(m - mn);
    float p = __expf(sc - mn);
    den = den * corr + p;
#pragma unroll
    for (int e = 0; e < 32; e += 2) {
      float2 vv = *(const float2*)&Vs[kk][e];
      acc[e] = acc[e] * corr + p * vv.x;
      acc[e + 1] = acc[e + 1] * corr + p * vv.y;
    }
    m = mn;
  }
  float inv = 1.f / den;
  float* op = Out + ((size_t)s * L + l) * 256 + h * 32;
#pragma unroll
  for (int e = 0; e < 32; e += 4) {
    float4 o;
    o.x = acc[e] * inv; o.y = acc[e + 1] * inv; o.z = acc[e + 2] * inv; o.w = acc[e + 3] * inv;
    *(float4*)(op + e) = o;
  }
}

// ---------------------------------------------------------------------------
// LayerNorm over last dim (256), one wave per row.
// MODE 0: Out[r] = LN(A[r] + Res[r])
// MODE 1: Out[r] = LN(A[r])
// MODE 2: Out[pr] = Res[pr] + 0.5*LN(A[r]) with r=(bc,t) -> pr=(b,t,c)
// ---------------------------------------------------------------------------
template <int MODE>
__global__ __launch_bounds__(256) void ln_k(const float* __restrict__ A,
                                            const float* __restrict__ Res,
                                            const float* __restrict__ w,
                                            const float* __restrict__ b,
                                            float* __restrict__ Out) {
  int row = (blockIdx.x << 2) + (threadIdx.x >> 6);
  int lane = threadIdx.x & 63;
  int j0 = lane << 2;
  float4 v = *(const float4*)&A[(size_t)row * 256 + j0];
  if (MODE == 0) {
    float4 r4 = *(const float4*)&Res[(size_t)row * 256 + j0];
    v.x += r4.x; v.y += r4.y; v.z += r4.z; v.w += r4.w;
  }
  float mean = wred_sum(v.x + v.y + v.z + v.w) * (1.f / 256.f);
  float dx = v.x - mean, dy = v.y - mean, dz = v.z - mean, dw = v.w - mean;
  float var = wred_sum(dx * dx + dy * dy + dz * dz + dw * dw) * (1.f / 256.f);
  float rstd = rsqrtf(var + LN_EPS);
  float4 wv = *(const float4*)&w[j0];
  float4 bv = *(const float4*)&b[j0];
  float4 o;
  o.x = dx * rstd * wv.x + bv.x;
  o.y = dy * rstd * wv.y + bv.y;
  o.z = dz * rstd * wv.z + bv.z;
  o.w = dw * rstd * wv.w + bv.w;
  if (MODE == 2) {
    int bc = row >> 7, t = row & 127;
    int pr = ((((bc >> 6) << 7) | t) << 6) | (bc & 63);
    float4 rv = *(const float4*)&Res[(size_t)pr * 256 + j0];
    o.x = rv.x + 0.5f * o.x;
    o.y = rv.y + 0.5f * o.y;
    o.z = rv.z + 0.5f * o.z;
    o.w = rv.w + 0.5f * o.w;
    *(float4*)&Out[(size_t)pr * 256 + j0] = o;
  } else {
    *(float4*)&Out[(size_t)row * 256 + j0] = o;
  }
}

// ---------------------------------------------------------------------------
// GroupNorm in place on cat[bc, 252, 128]; one wave per (bc, branch, group).
// ---------------------------------------------------------------------------
__global__ __launch_bounds__(256) void gn_k(float* __restrict__ catb,
                                            const float* __restrict__ gw,
                                            const float* __restrict__ gb) {
  int bc = blockIdx.x, ib = blockIdx.y;
  int grp = threadIdx.x >> 6;
  int lane = threadIdx.x & 63;
  float* base = catb + ((size_t)bc * 252 + ib * 28 + grp * 7) * 128;
  float vals[14];
  float s = 0.f, s2 = 0.f;
#pragma unroll
  for (int j = 0; j < 14; ++j) {
    float x = base[lane + (j << 6)];
    vals[j] = x;
    s += x;
    s2 = fmaf(x, x, s2);
  }
  s = wred_sum(s);
  s2 = wred_sum(s2);
  float mean = s * (1.f / 896.f);
  float var = s2 * (1.f / 896.f) - mean * mean;
  float rstd = rsqrtf(var + LN_EPS);
#pragma unroll
  for (int j = 0; j < 14; ++j) {
    int e = lane + (j << 6);
    int hp = grp * 7 + (e >> 7);
    base[e] = (vals[j] - mean) * rstd * gw[ib * 28 + hp] + gb[ib * 28 + hp];
  }
}

// Transpose (b,t,c,d) -> (b,c,t,d); one wave per output row.
__global__ __launch_bounds__(256) void transp_k(const float* __restrict__ In,
                                                float* __restrict__ Ot) {
  int row = (blockIdx.x << 2) + (threadIdx.x >> 6);  // (b,c,t) row
  int lane = threadIdx.x & 63;
  int bI = row >> 13, cI = (row >> 7) & 63, t = row & 127;
  int src = ((((bI << 7) | t) << 6) | cI);
  float4 v = *(const float4*)&In[(size_t)src * 256 + (lane << 2)];
  *(float4*)&Ot[(size_t)row * 256 + (lane << 2)] = v;
}

// Mean over heads of relpos -> bias[64*64]
__global__ void biasmean_k(const float* __restrict__ relpos, float* __restrict__ bout) {
  int idx = blockIdx.x * 256 + threadIdx.x;
  if (idx >= 4096) return;
  float sv = 0.f;
#pragma unroll
  for (int h = 0; h < 8; ++h) sv += relpos[h * 4096 + idx];
  bout[idx] = sv * 0.125f;
}

// conv weight transform: wT[branch][tau][hp][dch] (dch contiguous)
__global__ void wtrans_k(const float* __restrict__ w3, const float* __restrict__ w5,
                         const float* __restrict__ w7, float* __restrict__ wT) {
  int ib = blockIdx.y;  // 0..8
  int ki = ib / 3, di = ib % 3;
  int KT = (ki == 0) ? 3 : (ki == 1) ? 5 : 7;
  int base = (ki == 0) ? 0 : (ki == 1) ? 64512 : 172032;
  base += di * 7168 * KT;
  int sz = 7168 * KT;
  int idx = blockIdx.x * 256 + threadIdx.x;
  if (idx >= sz) return;
  int dch = idx & 255;
  int rest = idx >> 8;
  int tau = rest / 28, hp = rest % 28;
  const float* src = (ki == 0) ? w3 : (ki == 1) ? w5 : w7;
  wT[base + idx] = src[(((size_t)di * 28 + hp) * 256 + dch) * KT + tau];
}

// ---------------------------------------------------------------------------
// Multi-dilation conv + GELU. One block per (bc, dilation db = blockIdx.y).
// Input x2 in (b,t,c,d); output cat[bc, branch*28+hp, t].
// Weights pre-transposed (wave-uniform addresses -> scalar loads).
// Grid (512, 3): 1536 blocks -> ~4 blocks/CU (LDS-capped), 2x occupancy vs
// the fused-db version (was 512 blocks = 2/CU, VALUBusy 17.7%, 1061 us/disp).
// ---------------------------------------------------------------------------
template <int KT>
__global__ __launch_bounds__(256, 4) void conv_k(const float* __restrict__ x2,
                                                 const float* __restrict__ wTk,
                                                 const float* __restrict__ cb,
                                                 float* __restrict__ catb, int ibase) {
  const int bc = blockIdx.x;
  const int db = blockIdx.y;
  const int bI = bc >> 6, cI = bc & 63;
  const int tid = threadIdx.x;
  const int tt = tid & 127;
  const int h2 = tid >> 7;
  __shared__ float Xs[64][129];
  float acc[14];
#pragma unroll
  for (int u = 0; u < 14; ++u) acc[u] = 0.f;
  const int h2u = __builtin_amdgcn_readfirstlane(h2);
  const int DIL = 1 << db;
  const int PAD = ((KT - 1) << db) >> 1;
  const float* wdb = wTk + db * (7168 * KT);
#pragma unroll 1
  for (int ch0 = 0; ch0 < 256; ch0 += 64) {
    __syncthreads();
#pragma unroll
    for (int it = 0; it < 8; ++it) {
      int trow = (tid >> 4) + (it << 4);
      int dch = (tid & 15) << 2;
      float4 v = *(const float4*)&x2[(((size_t)bI * 128 + trow) * 64 + cI) * 256 + ch0 + dch];
      Xs[dch + 0][trow] = v.x; Xs[dch + 1][trow] = v.y;
      Xs[dch + 2][trow] = v.z; Xs[dch + 3][trow] = v.w;
    }
    __syncthreads();
#pragma unroll 1
    for (int tau = 0; tau < KT; ++tau) {
      int ts = tt + tau * DIL - PAD;
      bool ok = ((unsigned)ts) < 128u;
      const float* wrow = wdb + (tau * 28 + h2u) * 256 + ch0;
#pragma unroll
      for (int sub = 0; sub < 4; ++sub) {
        float xr[16];
#pragma unroll
        for (int j = 0; j < 16; ++j) xr[j] = ok ? Xs[(sub << 4) + j][ts] : 0.f;
        const float* wp = wrow + (sub << 4);
#pragma unroll
        for (int u = 0; u < 14; ++u) {
          const float* wpu = wp + (u << 9);
#pragma unroll
          for (int j = 0; j < 16; ++j) acc[u] = fmaf(xr[j], wpu[j], acc[u]);
        }
      }
    }
  }
#pragma unroll
  for (int u = 0; u < 14; ++u) {
    int hp = h2 + (u << 1);
    float v = gelu_f(acc[u] + cb[db * 28 + hp]);
    catb[((size_t)bc * 252 + (ibase + db) * 28 + hp) * 128 + tt] = v;
  }
}

// ---------------------------------------------------------------------------
extern "C" void kernel_launch(void* const* d_in, const int* in_sizes, int n_in,
                              void* d_out, int out_size, void* d_ws, size_t ws_size,
                              hipStream_t stream) {
  const float* x = (const float*)d_in[0];
  const float* sa_wqkv = (const float*)d_in[1];
  const float* sa_bqkv = (const float*)d_in[2];
  const float* sa_wout = (const float*)d_in[3];
  const float* sa_bout = (const float*)d_in[4];
  const float* sa_relpos = (const float*)d_in[5];
  const float* sa_ln_w = (const float*)d_in[6];
  const float* sa_ln_b = (const float*)d_in[7];
  const float* ta_wqkv = (const float*)d_in[8];
  const float* ta_bqkv = (const float*)d_in[9];
  const float* ta_wout = (const float*)d_in[10];
  const float* ta_bout = (const float*)d_in[11];
  const float* ta_ln_w = (const float*)d_in[12];
  const float* ta_ln_b = (const float*)d_in[13];
  const float* cw3 = (const float*)d_in[14];
  const float* cw5 = (const float*)d_in[15];
  const float* cw7 = (const float*)d_in[16];
  const float* cb3 = (const float*)d_in[17];
  const float* cb5 = (const float*)d_in[18];
  const float* cb7 = (const float*)d_in[19];
  const float* gn_w = (const float*)d_in[20];
  const float* gn_b = (const float*)d_in[21];
  const float* proj_w = (const float*)d_in[22];
  const float* proj_b = (const float*)d_in[23];
  const float* conv_ln_w = (const float*)d_in[24];
  const float* conv_ln_b = (const float*)d_in[25];
  const float* ff_w1 = (const float*)d_in[26];
  const float* ff_b1 = (const float*)d_in[27];
  const float* ff_w2 = (const float*)d_in[28];
  const float* ff_b2 = (const float*)d_in[29];
  const float* ff_ln_w = (const float*)d_in[30];
  const float* ff_ln_b = (const float*)d_in[31];
  const float* g1_w = (const float*)d_in[32];
  const float* g1_b = (const float*)d_in[33];
  const float* g2_w = (const float*)d_in[34];
  const float* g2_b = (const float*)d_in[35];
  const float* g3_w = (const float*)d_in[36];
  const float* g3_b = (const float*)d_in[37];
  float* O = (float*)d_out;  // used as scratch (xt, then x2) before final write

  // --- adaptive workspace layout ---
  // Fixed: A, B (full 65536x256), biasb 4096, wT 322560.
  // Stages: S1 = Rc*1024 (qkv/ffn-hidden chunk), S2 = Rc*256 (attn/h chunk).
  // Rc = largest power-of-two divisor of 65536 (>=128) that fits ws_size.
  const size_t FULL = 16777216;  // 65536*256
  size_t avail_f = ws_size / sizeof(float);
  const size_t fixed_f = 2 * FULL + 4096 + 322560;
  size_t rem = (avail_f > fixed_f) ? (avail_f - fixed_f) : 0;
  int Rc = 16384;
  while ((size_t)Rc * 1280 > rem && Rc > 128) Rc >>= 1;
  const int nc = 65536 / Rc;

  float* ws = (float*)d_ws;
  float* A = ws;
  float* B = A + FULL;
  float* S1 = B + FULL;
  float* S2 = S1 + (size_t)Rc * 1024;
  float* biasb = S2 + (size_t)Rc * 256;
  float* wT = biasb + 4096;
  const size_t CHD = (size_t)Rc * 256;

  // --- prep ---
  biasmean_k<<<16, 256, 0, stream>>>(sa_relpos, biasb);
  wtrans_k<<<dim3(196, 9), 256, 0, stream>>>(cw3, cw5, cw7, wT);

  // --- spatial attention: per chunk qkv->attn->outproj into A ---
  for (int c = 0; c < nc; ++c) {
    gemm_k<0><<<dim3(12, Rc / 128), 256, 0, stream>>>(x + c * CHD, sa_wqkv, sa_bqkv, S1, 256, 768);
    attn_k<64, true><<<dim3(Rc / 64, 8), 64, 0, stream>>>(S1, biasb, S2);
    gemm_k<0><<<dim3(4, Rc / 128), 256, 0, stream>>>(S2, sa_wout, sa_bout, A + c * CHD, 256, 256);
  }
  ln_k<0><<<16384, 256, 0, stream>>>(A, x, sa_ln_w, sa_ln_b, A);          // A = so
  gate_k<false><<<dim3(4, 512), 256, 0, stream>>>(A, x, g1_w, g1_b, B);   // B = x1

  // --- temporal attention (xt staged in d_out) ---
  transp_k<<<16384, 256, 0, stream>>>(B, O);                              // O = xt (b,c,t,d)
  for (int c = 0; c < nc; ++c) {
    gemm_k<0><<<dim3(12, Rc / 128), 256, 0, stream>>>(O + c * CHD, ta_wqkv, ta_bqkv, S1, 256, 768);
    attn_k<128, false><<<dim3(Rc / 128, 8), 128, 0, stream>>>(S1, nullptr, S2);
    gemm_k<0><<<dim3(4, Rc / 128), 256, 0, stream>>>(S2, ta_wout, ta_bout, A + c * CHD, 256, 256);
  }
  ln_k<0><<<16384, 256, 0, stream>>>(A, O, ta_ln_w, ta_ln_b, A);          // A = to (bct rows)
  gate_k<true><<<dim3(4, 512), 256, 0, stream>>>(A, B, g2_w, g2_b, O);    // O = x2 (btc rows)

  // --- multi-scale conv (grid.y = dilation) ---
  conv_k<3><<<dim3(512, 3), 256, 0, stream>>>(O, wT + 0, cb3, A, 0);
  conv_k<5><<<dim3(512, 3), 256, 0, stream>>>(O, wT + 64512, cb5, A, 3);
  conv_k<7><<<dim3(512, 3), 256, 0, stream>>>(O, wT + 172032, cb7, A, 6); // A = cat
  gn_k<<<dim3(512, 9), 256, 0, stream>>>(A, gn_w, gn_b);
  convproj_k<<<dim3(4, 512), 256, 0, stream>>>(A, proj_w, proj_b, B);     // B = co (bc,t rows)
  ln_k<2><<<16384, 256, 0, stream>>>(B, O, conv_ln_w, conv_ln_b, A);      // A = x3 (btc rows)

  // --- FFN + final gate, chunked; writes d_out ---
  for (int c = 0; c < nc; ++c) {
    gemm_k<1><<<dim3(16, Rc / 128), 256, 0, stream>>>(A + c * CHD, ff_w1, ff_b1, S1, 256, 1024);
    gemm_k<0><<<dim3(4, Rc / 128), 256, 0, stream>>>(S1, ff_w2, ff_b2, S2, 1024, 256);
    ln_k<1><<<Rc / 4, 256, 0, stream>>>(S2, nullptr, ff_ln_w, ff_ln_b, S2);
    gate_k<false><<<dim3(4, Rc / 128), 256, 0, stream>>>(S2, A + c * CHD, g3_w, g3_b, O + c * CHD);
  }
}

// Round 7
// 4228.831 us; speedup vs baseline: 1.6501x; 1.6501x over previous
//
#include <hip/hip_runtime.h>
#include <cmath>

#define DEV __device__ __forceinline__

constexpr float LN_EPS = 1e-5f;

typedef __attribute__((ext_vector_type(8))) short short8;
typedef __attribute__((ext_vector_type(4))) float f32x4;

DEV float gelu_f(float x) { return 0.5f * x * (1.f + erff(x * 0.70710678118654752440f)); }
DEV float sigmoid_f(float x) { return 1.f / (1.f + __expf(-x)); }

DEV short f2bf(float x) {  // fp32 -> bf16 bits, round-to-nearest-even
  unsigned u = __builtin_bit_cast(unsigned, x);
  unsigned r = (u + 0x7FFFu + ((u >> 16) & 1u)) >> 16;
  return (short)r;
}

DEV float wred_sum(float v) {
#pragma unroll
  for (int m = 1; m < 64; m <<= 1) v += __shfl_xor(v, m, 64);
  return v;
}

// r = (b*128 + t)*64 + c  ->  (b*64 + c)*128 + t
DEV int permrow_btc_to_bct(int r) {
  int bI = r >> 13, t = (r >> 6) & 127, cI = r & 63;
  return ((((bI << 6) | cI) << 7) | t);
}

// ---------------------------------------------------------------------------
// MFMA bf16 GEMM: C[r,o] = act(sum_k A[r,k]*W[o,k] + bias[o])
// Block tile 128x64, 4 waves (2M x 2N), each wave 4x2 mfma_f32_16x16x32_bf16.
// TRANSA=0: A row-major [rows][K], K % 32 == 0.
// TRANSA=1: A is cat-layout [bc][K][128] with bc = blockIdx.y (128 rows/bc),
//           K arbitrary (zero-padded to 32).
// fp32 inputs converted to bf16 in-register during LDS staging.
// ---------------------------------------------------------------------------
template <int ACT, int TRANSA>  // ACT: 0 none, 1 gelu
__global__ __launch_bounds__(256, 2) void mgemm_k(const float* __restrict__ A,
                                                  const float* __restrict__ W,
                                                  const float* __restrict__ bias,
                                                  float* __restrict__ C, int K, int M) {
  __shared__ short As[128][40];  // row stride 80B (20 banks) -> ~2-way max
  __shared__ short Ws[64][40];
  const int tid = threadIdx.x;
  const int row0 = blockIdx.y << 7;
  const int col0 = blockIdx.x << 6;
  const int l = tid & 63;
  const int wid = tid >> 6;
  const int wm = wid >> 1, wn = wid & 1;
  const int fr = l & 15;
  const int fkb = (l >> 4) << 3;  // k element offset of fragment
  f32x4 acc[4][2];
#pragma unroll
  for (int mt = 0; mt < 4; ++mt)
#pragma unroll
    for (int nt = 0; nt < 2; ++nt) acc[mt][nt] = f32x4{0.f, 0.f, 0.f, 0.f};

  const int Kpad = (K + 31) & ~31;
  for (int k0 = 0; k0 < Kpad; k0 += 32) {
    float fa[16];
    float fw[8];
    int ar, kh, kk, tg;
    if (TRANSA == 0) {
      ar = tid >> 1; kh = (tid & 1) << 4;
      const float* p = A + (size_t)(row0 + ar) * K + k0 + kh;
      float4 a0 = *(const float4*)p;
      float4 a1 = *(const float4*)(p + 4);
      float4 a2 = *(const float4*)(p + 8);
      float4 a3 = *(const float4*)(p + 12);
      fa[0]=a0.x; fa[1]=a0.y; fa[2]=a0.z; fa[3]=a0.w;
      fa[4]=a1.x; fa[5]=a1.y; fa[6]=a1.z; fa[7]=a1.w;
      fa[8]=a2.x; fa[9]=a2.y; fa[10]=a2.z; fa[11]=a2.w;
      fa[12]=a3.x; fa[13]=a3.y; fa[14]=a3.z; fa[15]=a3.w;
    } else {
      kk = tid >> 3; tg = (tid & 7) << 4;  // kk: 0..31, tg: 16-row t segment
      if (k0 + kk < K) {
        const float* p = A + ((size_t)(row0 >> 7) * K + k0 + kk) * 128 + tg;
        float4 a0 = *(const float4*)p;
        float4 a1 = *(const float4*)(p + 4);
        float4 a2 = *(const float4*)(p + 8);
        float4 a3 = *(const float4*)(p + 12);
        fa[0]=a0.x; fa[1]=a0.y; fa[2]=a0.z; fa[3]=a0.w;
        fa[4]=a1.x; fa[5]=a1.y; fa[6]=a1.z; fa[7]=a1.w;
        fa[8]=a2.x; fa[9]=a2.y; fa[10]=a2.z; fa[11]=a2.w;
        fa[12]=a3.x; fa[13]=a3.y; fa[14]=a3.z; fa[15]=a3.w;
      } else {
#pragma unroll
        for (int i = 0; i < 16; ++i) fa[i] = 0.f;
      }
    }
    const int wr = tid >> 2, kw = (tid & 3) << 3;
    if (TRANSA == 0) {
      const float* q = W + (size_t)(col0 + wr) * K + k0 + kw;
      float4 w0 = *(const float4*)q;
      float4 w1 = *(const float4*)(q + 4);
      fw[0]=w0.x; fw[1]=w0.y; fw[2]=w0.z; fw[3]=w0.w;
      fw[4]=w1.x; fw[5]=w1.y; fw[6]=w1.z; fw[7]=w1.w;
    } else {
      const float* q = W + (size_t)(col0 + wr) * K + k0 + kw;
#pragma unroll
      for (int j = 0; j < 8; ++j) fw[j] = (k0 + kw + j < K) ? q[j] : 0.f;
    }
    __syncthreads();
    if (TRANSA == 0) {
      short8 p0, p1;
#pragma unroll
      for (int j = 0; j < 8; ++j) { p0[j] = f2bf(fa[j]); p1[j] = f2bf(fa[j + 8]); }
      *(short8*)&As[ar][kh] = p0;
      *(short8*)&As[ar][kh + 8] = p1;
    } else {
#pragma unroll
      for (int i = 0; i < 16; ++i) As[tg + i][kk] = f2bf(fa[i]);
    }
    {
      short8 pw;
#pragma unroll
      for (int j = 0; j < 8; ++j) pw[j] = f2bf(fw[j]);
      *(short8*)&Ws[wr][kw] = pw;
    }
    __syncthreads();
    short8 af[4], bfr[2];
#pragma unroll
    for (int mt = 0; mt < 4; ++mt) af[mt] = *(const short8*)&As[wm * 64 + mt * 16 + fr][fkb];
#pragma unroll
    for (int nt = 0; nt < 2; ++nt) bfr[nt] = *(const short8*)&Ws[wn * 32 + nt * 16 + fr][fkb];
#pragma unroll
    for (int mt = 0; mt < 4; ++mt)
#pragma unroll
      for (int nt = 0; nt < 2; ++nt)
        acc[mt][nt] = __builtin_amdgcn_mfma_f32_16x16x32_bf16(af[mt], bfr[nt], acc[mt][nt], 0, 0, 0);
  }
  // epilogue: C/D map col = lane&15, row = (lane>>4)*4 + j   [m89-verified]
#pragma unroll
  for (int nt = 0; nt < 2; ++nt) {
    const int col = col0 + wn * 32 + nt * 16 + fr;
    const float bv = bias[col];
#pragma unroll
    for (int mt = 0; mt < 4; ++mt) {
      const int rb = row0 + wm * 64 + mt * 16 + ((l >> 4) << 2);
#pragma unroll
      for (int j = 0; j < 4; ++j) {
        float v = acc[mt][nt][j] + bv;
        if (ACT == 1) v = gelu_f(v);
        C[(size_t)(rb + j) * M + col] = v;
      }
    }
  }
}

// ---------------------------------------------------------------------------
// MFMA gate: out[r,o] = y*g + res*(1-g), g = sigmoid([y,res]@W^T + b).
// K = 512 (Y cols 0-255, R cols 256-511), M = 256.
// ---------------------------------------------------------------------------
template <bool PERM>
__global__ __launch_bounds__(256, 2) void mgate_k(const float* __restrict__ Y,
                                                  const float* __restrict__ R,
                                                  const float* __restrict__ W,
                                                  const float* __restrict__ bias,
                                                  float* __restrict__ Out) {
  __shared__ short As[128][40];
  __shared__ short Ws[64][40];
  const int tid = threadIdx.x;
  const int row0 = blockIdx.y << 7;
  const int col0 = blockIdx.x << 6;
  const int l = tid & 63;
  const int wid = tid >> 6;
  const int wm = wid >> 1, wn = wid & 1;
  const int fr = l & 15;
  const int fkb = (l >> 4) << 3;
  f32x4 acc[4][2];
#pragma unroll
  for (int mt = 0; mt < 4; ++mt)
#pragma unroll
    for (int nt = 0; nt < 2; ++nt) acc[mt][nt] = f32x4{0.f, 0.f, 0.f, 0.f};

  const int ar = tid >> 1, kh = (tid & 1) << 4;
  const int arow = row0 + ar;
  const int yrow = PERM ? permrow_btc_to_bct(arow) : arow;
  const int wr = tid >> 2, kw = (tid & 3) << 3;
  for (int k0 = 0; k0 < 512; k0 += 32) {
    const float* p = (k0 < 256) ? (Y + (size_t)yrow * 256 + k0 + kh)
                                : (R + (size_t)arow * 256 + (k0 - 256) + kh);
    float4 a0 = *(const float4*)p;
    float4 a1 = *(const float4*)(p + 4);
    float4 a2 = *(const float4*)(p + 8);
    float4 a3 = *(const float4*)(p + 12);
    const float* q = W + (size_t)(col0 + wr) * 512 + k0 + kw;
    float4 w0 = *(const float4*)q;
    float4 w1 = *(const float4*)(q + 4);
    __syncthreads();
    short8 p0, p1, pw;
    p0[0]=f2bf(a0.x); p0[1]=f2bf(a0.y); p0[2]=f2bf(a0.z); p0[3]=f2bf(a0.w);
    p0[4]=f2bf(a1.x); p0[5]=f2bf(a1.y); p0[6]=f2bf(a1.z); p0[7]=f2bf(a1.w);
    p1[0]=f2bf(a2.x); p1[1]=f2bf(a2.y); p1[2]=f2bf(a2.z); p1[3]=f2bf(a2.w);
    p1[4]=f2bf(a3.x); p1[5]=f2bf(a3.y); p1[6]=f2bf(a3.z); p1[7]=f2bf(a3.w);
    pw[0]=f2bf(w0.x); pw[1]=f2bf(w0.y); pw[2]=f2bf(w0.z); pw[3]=f2bf(w0.w);
    pw[4]=f2bf(w1.x); pw[5]=f2bf(w1.y); pw[6]=f2bf(w1.z); pw[7]=f2bf(w1.w);
    *(short8*)&As[ar][kh] = p0;
    *(short8*)&As[ar][kh + 8] = p1;
    *(short8*)&Ws[wr][kw] = pw;
    __syncthreads();
    short8 af[4], bfr[2];
#pragma unroll
    for (int mt = 0; mt < 4; ++mt) af[mt] = *(const short8*)&As[wm * 64 + mt * 16 + fr][fkb];
#pragma unroll
    for (int nt = 0; nt < 2; ++nt) bfr[nt] = *(const short8*)&Ws[wn * 32 + nt * 16 + fr][fkb];
#pragma unroll
    for (int mt = 0; mt < 4; ++mt)
#pragma unroll
      for (int nt = 0; nt < 2; ++nt)
        acc[mt][nt] = __builtin_amdgcn_mfma_f32_16x16x32_bf16(af[mt], bfr[nt], acc[mt][nt], 0, 0, 0);
  }
#pragma unroll
  for (int nt = 0; nt < 2; ++nt) {
    const int col = col0 + wn * 32 + nt * 16 + fr;
    const float bv = bias[col];
#pragma unroll
    for (int mt = 0; mt < 4; ++mt) {
      const int rb = row0 + wm * 64 + mt * 16 + ((l >> 4) << 2);
#pragma unroll
      for (int j = 0; j < 4; ++j) {
        const int r = rb + j;
        const int yr = PERM ? permrow_btc_to_bct(r) : r;
        float g = sigmoid_f(acc[mt][nt][j] + bv);
        float yv = Y[(size_t)yr * 256 + col];
        float rv = R[(size_t)r * 256 + col];
        Out[(size_t)r * 256 + col] = yv * g + rv * (1.f - g);
      }
    }
  }
}

// ---------------------------------------------------------------------------
// Attention (online softmax), one wave-lane per query row. L=64 (bias) or 128.
// qkv rows: [seq*L + l][768] with q|k|v each 256 = 8 heads * 32.
// ---------------------------------------------------------------------------
template <int L, bool HASB>
__global__ __launch_bounds__(L) void attn_k(const float* __restrict__ qkv,
                                            const float* __restrict__ bmat,
                                            float* __restrict__ Out) {
  __shared__ float Ks[L][34];
  __shared__ float Vs[L][34];
  __shared__ float Bs[HASB ? 64 * 65 : 1];
  const int s = blockIdx.x, h = blockIdx.y, l = threadIdx.x;
  const float* rowp = qkv + ((size_t)s * L + l) * 768 + h * 32;
  float q[32];
#pragma unroll
  for (int e = 0; e < 32; e += 4) {
    float4 t4 = *(const float4*)(rowp + e);
    q[e] = t4.x; q[e + 1] = t4.y; q[e + 2] = t4.z; q[e + 3] = t4.w;
    float4 k4 = *(const float4*)(rowp + 256 + e);
    Ks[l][e] = k4.x; Ks[l][e + 1] = k4.y; Ks[l][e + 2] = k4.z; Ks[l][e + 3] = k4.w;
    float4 v4 = *(const float4*)(rowp + 512 + e);
    Vs[l][e] = v4.x; Vs[l][e + 1] = v4.y; Vs[l][e + 2] = v4.z; Vs[l][e + 3] = v4.w;
  }
  if (HASB) {
#pragma unroll 1
    for (int j = 0; j < 64; ++j) Bs[l * 65 + j] = bmat[l * 64 + j];
  }
  __syncthreads();
  float m = -3.0e38f, den = 0.f;
  float acc[32];
#pragma unroll
  for (int e = 0; e < 32; ++e) acc[e] = 0.f;
  for (int kk = 0; kk < L; ++kk) {
    float sd = 0.f;
#pragma unroll
    for (int e = 0; e < 32; e += 2) {
      float2 kv = *(const float2*)&Ks[kk][e];
      sd = fmaf(q[e], kv.x, sd);
      sd = fmaf(q[e + 1], kv.y, sd);
    }
    float sc = sd * 0.17677669529663687f;
    if (HASB) sc += Bs[l * 65 + kk];
    float mn = fmaxf(m, sc);
    float corr = __expf(m - mn);
    float p = __expf(sc - mn);
    den = den * corr + p;
#pragma unroll
    for (int e = 0; e < 32; e += 2) {
      float2 vv = *(const float2*)&Vs[kk][e];
      acc[e] = acc[e] * corr + p * vv.x;
      acc[e + 1] = acc[e + 1] * corr + p * vv.y;
    }
    m = mn;
  }
  float inv = 1.f / den;
  float* op = Out + ((size_t)s * L + l) * 256 + h * 32;
#pragma unroll
  for (int e = 0; e < 32; e += 4) {
    float4 o;
    o.x = acc[e] * inv; o.y = acc[e + 1] * inv; o.z = acc[e + 2] * inv; o.w = acc[e + 3] * inv;
    *(float4*)(op + e) = o;
  }
}

// ---------------------------------------------------------------------------
// LayerNorm over last dim (256), one wave per row.
// MODE 0: Out[r] = LN(A[r] + Res[r])
// MODE 1: Out[r] = LN(A[r])
// MODE 2: Out[pr] = Res[pr] + 0.5*LN(A[r]) with r=(bc,t) -> pr=(b,t,c)
// ---------------------------------------------------------------------------
template <int MODE>
__global__ __launch_bounds__(256) void ln_k(const float* __restrict__ A,
                                            const float* __restrict__ Res,
                                            const float* __restrict__ w,
                                            const float* __restrict__ b,
                                            float* __restrict__ Out) {
  int row = (blockIdx.x << 2) + (threadIdx.x >> 6);
  int lane = threadIdx.x & 63;
  int j0 = lane << 2;
  float4 v = *(const float4*)&A[(size_t)row * 256 + j0];
  if (MODE == 0) {
    float4 r4 = *(const float4*)&Res[(size_t)row * 256 + j0];
    v.x += r4.x; v.y += r4.y; v.z += r4.z; v.w += r4.w;
  }
  float mean = wred_sum(v.x + v.y + v.z + v.w) * (1.f / 256.f);
  float dx = v.x - mean, dy = v.y - mean, dz = v.z - mean, dw = v.w - mean;
  float var = wred_sum(dx * dx + dy * dy + dz * dz + dw * dw) * (1.f / 256.f);
  float rstd = rsqrtf(var + LN_EPS);
  float4 wv = *(const float4*)&w[j0];
  float4 bv = *(const float4*)&b[j0];
  float4 o;
  o.x = dx * rstd * wv.x + bv.x;
  o.y = dy * rstd * wv.y + bv.y;
  o.z = dz * rstd * wv.z + bv.z;
  o.w = dw * rstd * wv.w + bv.w;
  if (MODE == 2) {
    int bc = row >> 7, t = row & 127;
    int pr = ((((bc >> 6) << 7) | t) << 6) | (bc & 63);
    float4 rv = *(const float4*)&Res[(size_t)pr * 256 + j0];
    o.x = rv.x + 0.5f * o.x;
    o.y = rv.y + 0.5f * o.y;
    o.z = rv.z + 0.5f * o.z;
    o.w = rv.w + 0.5f * o.w;
    *(float4*)&Out[(size_t)pr * 256 + j0] = o;
  } else {
    *(float4*)&Out[(size_t)row * 256 + j0] = o;
  }
}

// ---------------------------------------------------------------------------
// GroupNorm in place on cat[bc, 252, 128]; one wave per (bc, branch, group).
// ---------------------------------------------------------------------------
__global__ __launch_bounds__(256) void gn_k(float* __restrict__ catb,
                                            const float* __restrict__ gw,
                                            const float* __restrict__ gb) {
  int bc = blockIdx.x, ib = blockIdx.y;
  int grp = threadIdx.x >> 6;
  int lane = threadIdx.x & 63;
  float* base = catb + ((size_t)bc * 252 + ib * 28 + grp * 7) * 128;
  float vals[14];
  float s = 0.f, s2 = 0.f;
#pragma unroll
  for (int j = 0; j < 14; ++j) {
    float x = base[lane + (j << 6)];
    vals[j] = x;
    s += x;
    s2 = fmaf(x, x, s2);
  }
  s = wred_sum(s);
  s2 = wred_sum(s2);
  float mean = s * (1.f / 896.f);
  float var = s2 * (1.f / 896.f) - mean * mean;
  float rstd = rsqrtf(var + LN_EPS);
#pragma unroll
  for (int j = 0; j < 14; ++j) {
    int e = lane + (j << 6);
    int hp = grp * 7 + (e >> 7);
    base[e] = (vals[j] - mean) * rstd * gw[ib * 28 + hp] + gb[ib * 28 + hp];
  }
}

// Transpose (b,t,c,d) -> (b,c,t,d); one wave per output row.
__global__ __launch_bounds__(256) void transp_k(const float* __restrict__ In,
                                                float* __restrict__ Ot) {
  int row = (blockIdx.x << 2) + (threadIdx.x >> 6);  // (b,c,t) row
  int lane = threadIdx.x & 63;
  int bI = row >> 13, cI = (row >> 7) & 63, t = row & 127;
  int src = ((((bI << 7) | t) << 6) | cI);
  float4 v = *(const float4*)&In[(size_t)src * 256 + (lane << 2)];
  *(float4*)&Ot[(size_t)row * 256 + (lane << 2)] = v;
}

// Mean over heads of relpos -> bias[64*64]
__global__ void biasmean_k(const float* __restrict__ relpos, float* __restrict__ bout) {
  int idx = blockIdx.x * 256 + threadIdx.x;
  if (idx >= 4096) return;
  float sv = 0.f;
#pragma unroll
  for (int h = 0; h < 8; ++h) sv += relpos[h * 4096 + idx];
  bout[idx] = sv * 0.125f;
}

// conv weight transform: wT[branch][tau][hp][dch] (dch contiguous)
__global__ void wtrans_k(const float* __restrict__ w3, const float* __restrict__ w5,
                         const float* __restrict__ w7, float* __restrict__ wT) {
  int ib = blockIdx.y;  // 0..8
  int ki = ib / 3, di = ib % 3;
  int KT = (ki == 0) ? 3 : (ki == 1) ? 5 : 7;
  int base = (ki == 0) ? 0 : (ki == 1) ? 64512 : 172032;
  base += di * 7168 * KT;
  int sz = 7168 * KT;
  int idx = blockIdx.x * 256 + threadIdx.x;
  if (idx >= sz) return;
  int dch = idx & 255;
  int rest = idx >> 8;
  int tau = rest / 28, hp = rest % 28;
  const float* src = (ki == 0) ? w3 : (ki == 1) ? w5 : w7;
  wT[base + idx] = src[(((size_t)di * 28 + hp) * 256 + dch) * KT + tau];
}

// ---------------------------------------------------------------------------
// Multi-dilation conv + GELU (round-5 form: fused db loop, unroll-1 sub loop;
// the db-split/unrolled variant spilled to scratch: WRITE_SIZE 21.5MB->1.16GB).
// ---------------------------------------------------------------------------
template <int KT>
__global__ __launch_bounds__(256, 2) void conv_k(const float* __restrict__ x2,
                                                 const float* __restrict__ wTk,
                                                 const float* __restrict__ cb,
                                                 float* __restrict__ catb, int ibase) {
  const int bc = blockIdx.x;
  const int bI = bc >> 6, cI = bc & 63;
  const int tid = threadIdx.x;
  const int tt = tid & 127;
  const int h2 = tid >> 7;
  __shared__ float Xs[64][129];
  float acc[3][14];
#pragma unroll
  for (int a = 0; a < 3; ++a)
#pragma unroll
    for (int u = 0; u < 14; ++u) acc[a][u] = 0.f;
  const int h2u = __builtin_amdgcn_readfirstlane(h2);
#pragma unroll 1
  for (int ch0 = 0; ch0 < 256; ch0 += 64) {
    __syncthreads();
#pragma unroll
    for (int it = 0; it < 8; ++it) {
      int trow = (tid >> 4) + (it << 4);
      int dch = (tid & 15) << 2;
      float4 v = *(const float4*)&x2[(((size_t)bI * 128 + trow) * 64 + cI) * 256 + ch0 + dch];
      Xs[dch + 0][trow] = v.x; Xs[dch + 1][trow] = v.y;
      Xs[dch + 2][trow] = v.z; Xs[dch + 3][trow] = v.w;
    }
    __syncthreads();
#pragma unroll
    for (int db = 0; db < 3; ++db) {
      const int DIL = 1 << db;
      const int PAD = ((KT - 1) << db) >> 1;
#pragma unroll 1
      for (int tau = 0; tau < KT; ++tau) {
        int ts = tt + tau * DIL - PAD;
        bool ok = ((unsigned)ts) < 128u;
        const float* wrow = wTk + db * (7168 * KT) + (tau * 28 + h2u) * 256 + ch0;
#pragma unroll 1
        for (int sub = 0; sub < 4; ++sub) {
          float xr[16];
#pragma unroll
          for (int j = 0; j < 16; ++j) xr[j] = ok ? Xs[(sub << 4) + j][ts] : 0.f;
          const float* wp = wrow + (sub << 4);
#pragma unroll
          for (int u = 0; u < 14; ++u) {
            const float* wpu = wp + (u << 9);
#pragma unroll
            for (int j = 0; j < 16; ++j) acc[db][u] = fmaf(xr[j], wpu[j], acc[db][u]);
          }
        }
      }
    }
  }
#pragma unroll
  for (int db = 0; db < 3; ++db)
#pragma unroll
    for (int u = 0; u < 14; ++u) {
      int hp = h2 + (u << 1);
      float v = gelu_f(acc[db][u] + cb[db * 28 + hp]);
      catb[((size_t)bc * 252 + (ibase + db) * 28 + hp) * 128 + tt] = v;
    }
}

// ---------------------------------------------------------------------------
extern "C" void kernel_launch(void* const* d_in, const int* in_sizes, int n_in,
                              void* d_out, int out_size, void* d_ws, size_t ws_size,
                              hipStream_t stream) {
  const float* x = (const float*)d_in[0];
  const float* sa_wqkv = (const float*)d_in[1];
  const float* sa_bqkv = (const float*)d_in[2];
  const float* sa_wout = (const float*)d_in[3];
  const float* sa_bout = (const float*)d_in[4];
  const float* sa_relpos = (const float*)d_in[5];
  const float* sa_ln_w = (const float*)d_in[6];
  const float* sa_ln_b = (const float*)d_in[7];
  const float* ta_wqkv = (const float*)d_in[8];
  const float* ta_bqkv = (const float*)d_in[9];
  const float* ta_wout = (const float*)d_in[10];
  const float* ta_bout = (const float*)d_in[11];
  const float* ta_ln_w = (const float*)d_in[12];
  const float* ta_ln_b = (const float*)d_in[13];
  const float* cw3 = (const float*)d_in[14];
  const float* cw5 = (const float*)d_in[15];
  const float* cw7 = (const float*)d_in[16];
  const float* cb3 = (const float*)d_in[17];
  const float* cb5 = (const float*)d_in[18];
  const float* cb7 = (const float*)d_in[19];
  const float* gn_w = (const float*)d_in[20];
  const float* gn_b = (const float*)d_in[21];
  const float* proj_w = (const float*)d_in[22];
  const float* proj_b = (const float*)d_in[23];
  const float* conv_ln_w = (const float*)d_in[24];
  const float* conv_ln_b = (const float*)d_in[25];
  const float* ff_w1 = (const float*)d_in[26];
  const float* ff_b1 = (const float*)d_in[27];
  const float* ff_w2 = (const float*)d_in[28];
  const float* ff_b2 = (const float*)d_in[29];
  const float* ff_ln_w = (const float*)d_in[30];
  const float* ff_ln_b = (const float*)d_in[31];
  const float* g1_w = (const float*)d_in[32];
  const float* g1_b = (const float*)d_in[33];
  const float* g2_w = (const float*)d_in[34];
  const float* g2_b = (const float*)d_in[35];
  const float* g3_w = (const float*)d_in[36];
  const float* g3_b = (const float*)d_in[37];
  float* O = (float*)d_out;  // used as scratch (xt, then x2) before final write

  // --- adaptive workspace layout (unchanged from round 5) ---
  const size_t FULL = 16777216;  // 65536*256
  size_t avail_f = ws_size / sizeof(float);
  const size_t fixed_f = 2 * FULL + 4096 + 322560;
  size_t rem = (avail_f > fixed_f) ? (avail_f - fixed_f) : 0;
  int Rc = 16384;
  while ((size_t)Rc * 1280 > rem && Rc > 128) Rc >>= 1;
  const int nc = 65536 / Rc;

  float* ws = (float*)d_ws;
  float* A = ws;
  float* B = A + FULL;
  float* S1 = B + FULL;
  float* S2 = S1 + (size_t)Rc * 1024;
  float* biasb = S2 + (size_t)Rc * 256;
  float* wT = biasb + 4096;
  const size_t CHD = (size_t)Rc * 256;

  // --- prep ---
  biasmean_k<<<16, 256, 0, stream>>>(sa_relpos, biasb);
  wtrans_k<<<dim3(196, 9), 256, 0, stream>>>(cw3, cw5, cw7, wT);

  // --- spatial attention: per chunk qkv->attn->outproj into A ---
  for (int c = 0; c < nc; ++c) {
    mgemm_k<0, 0><<<dim3(12, Rc / 128), 256, 0, stream>>>(x + c * CHD, sa_wqkv, sa_bqkv, S1, 256, 768);
    attn_k<64, true><<<dim3(Rc / 64, 8), 64, 0, stream>>>(S1, biasb, S2);
    mgemm_k<0, 0><<<dim3(4, Rc / 128), 256, 0, stream>>>(S2, sa_wout, sa_bout, A + c * CHD, 256, 256);
  }
  ln_k<0><<<16384, 256, 0, stream>>>(A, x, sa_ln_w, sa_ln_b, A);          // A = so
  mgate_k<false><<<dim3(4, 512), 256, 0, stream>>>(A, x, g1_w, g1_b, B);  // B = x1

  // --- temporal attention (xt staged in d_out) ---
  transp_k<<<16384, 256, 0, stream>>>(B, O);                              // O = xt (b,c,t,d)
  for (int c = 0; c < nc; ++c) {
    mgemm_k<0, 0><<<dim3(12, Rc / 128), 256, 0, stream>>>(O + c * CHD, ta_wqkv, ta_bqkv, S1, 256, 768);
    attn_k<128, false><<<dim3(Rc / 128, 8), 128, 0, stream>>>(S1, nullptr, S2);
    mgemm_k<0, 0><<<dim3(4, Rc / 128), 256, 0, stream>>>(S2, ta_wout, ta_bout, A + c * CHD, 256, 256);
  }
  ln_k<0><<<16384, 256, 0, stream>>>(A, O, ta_ln_w, ta_ln_b, A);          // A = to (bct rows)
  mgate_k<true><<<dim3(4, 512), 256, 0, stream>>>(A, B, g2_w, g2_b, O);   // O = x2 (btc rows)

  // --- multi-scale conv ---
  conv_k<3><<<512, 256, 0, stream>>>(O, wT + 0, cb3, A, 0);
  conv_k<5><<<512, 256, 0, stream>>>(O, wT + 64512, cb5, A, 3);
  conv_k<7><<<512, 256, 0, stream>>>(O, wT + 172032, cb7, A, 6);          // A = cat
  gn_k<<<dim3(512, 9), 256, 0, stream>>>(A, gn_w, gn_b);
  mgemm_k<0, 1><<<dim3(4, 512), 256, 0, stream>>>(A, proj_w, proj_b, B, 252, 256);  // B = co
  ln_k<2><<<16384, 256, 0, stream>>>(B, O, conv_ln_w, conv_ln_b, A);      // A = x3 (btc rows)

  // --- FFN + final gate, chunked; writes d_out ---
  for (int c = 0; c < nc; ++c) {
    mgemm_k<1, 0><<<dim3(16, Rc / 128), 256, 0, stream>>>(A + c * CHD, ff_w1, ff_b1, S1, 256, 1024);
    mgemm_k<0, 0><<<dim3(4, Rc / 128), 256, 0, stream>>>(S1, ff_w2, ff_b2, S2, 1024, 256);
    ln_k<1><<<Rc / 4, 256, 0, stream>>>(S2, nullptr, ff_ln_w, ff_ln_b, S2);
    mgate_k<false><<<dim3(4, Rc / 128), 256, 0, stream>>>(S2, A + c * CHD, g3_w, g3_b, O + c * CHD);
  }
}

// Round 9
// 2169.492 us; speedup vs baseline: 3.2165x; 1.9492x over previous
//
#include <hip/hip_runtime.h>
#include <cmath>

#define DEV __device__ __forceinline__

constexpr float LN_EPS = 1e-5f;

typedef __attribute__((ext_vector_type(8))) short short8;
typedef __attribute__((ext_vector_type(4))) short short4v;
typedef __attribute__((ext_vector_type(4))) float f32x4;

DEV float gelu_f(float x) { return 0.5f * x * (1.f + erff(x * 0.70710678118654752440f)); }
DEV float sigmoid_f(float x) { return 1.f / (1.f + __expf(-x)); }

DEV short f2bf(float x) {  // fp32 -> bf16 bits, round-to-nearest-even
  unsigned u = __builtin_bit_cast(unsigned, x);
  unsigned r = (u + 0x7FFFu + ((u >> 16) & 1u)) >> 16;
  return (short)r;
}

DEV float wred_sum(float v) {
#pragma unroll
  for (int m = 1; m < 64; m <<= 1) v += __shfl_xor(v, m, 64);
  return v;
}

// r = (b*128 + t)*64 + c  ->  (b*64 + c)*128 + t
DEV int permrow_btc_to_bct(int r) {
  int bI = r >> 13, t = (r >> 6) & 127, cI = r & 63;
  return ((((bI << 6) | cI) << 7) | t);
}

// ---------------------------------------------------------------------------
// MFMA bf16 GEMM (HW-verified): C = act(A W^T + b)
// ---------------------------------------------------------------------------
template <int ACT, int TRANSA>  // ACT: 0 none, 1 gelu
__global__ __launch_bounds__(256, 2) void mgemm_k(const float* __restrict__ A,
                                                  const float* __restrict__ W,
                                                  const float* __restrict__ bias,
                                                  float* __restrict__ C, int K, int M) {
  __shared__ short As[128][40];
  __shared__ short Ws[64][40];
  const int tid = threadIdx.x;
  const int row0 = blockIdx.y << 7;
  const int col0 = blockIdx.x << 6;
  const int l = tid & 63;
  const int wid = tid >> 6;
  const int wm = wid >> 1, wn = wid & 1;
  const int fr = l & 15;
  const int fkb = (l >> 4) << 3;
  f32x4 acc[4][2];
#pragma unroll
  for (int mt = 0; mt < 4; ++mt)
#pragma unroll
    for (int nt = 0; nt < 2; ++nt) acc[mt][nt] = f32x4{0.f, 0.f, 0.f, 0.f};

  const int Kpad = (K + 31) & ~31;
  for (int k0 = 0; k0 < Kpad; k0 += 32) {
    float fa[16];
    float fw[8];
    int ar, kh, kk, tg;
    if (TRANSA == 0) {
      ar = tid >> 1; kh = (tid & 1) << 4;
      const float* p = A + (size_t)(row0 + ar) * K + k0 + kh;
      float4 a0 = *(const float4*)p;
      float4 a1 = *(const float4*)(p + 4);
      float4 a2 = *(const float4*)(p + 8);
      float4 a3 = *(const float4*)(p + 12);
      fa[0]=a0.x; fa[1]=a0.y; fa[2]=a0.z; fa[3]=a0.w;
      fa[4]=a1.x; fa[5]=a1.y; fa[6]=a1.z; fa[7]=a1.w;
      fa[8]=a2.x; fa[9]=a2.y; fa[10]=a2.z; fa[11]=a2.w;
      fa[12]=a3.x; fa[13]=a3.y; fa[14]=a3.z; fa[15]=a3.w;
    } else {
      kk = tid >> 3; tg = (tid & 7) << 4;
      if (k0 + kk < K) {
        const float* p = A + ((size_t)(row0 >> 7) * K + k0 + kk) * 128 + tg;
        float4 a0 = *(const float4*)p;
        float4 a1 = *(const float4*)(p + 4);
        float4 a2 = *(const float4*)(p + 8);
        float4 a3 = *(const float4*)(p + 12);
        fa[0]=a0.x; fa[1]=a0.y; fa[2]=a0.z; fa[3]=a0.w;
        fa[4]=a1.x; fa[5]=a1.y; fa[6]=a1.z; fa[7]=a1.w;
        fa[8]=a2.x; fa[9]=a2.y; fa[10]=a2.z; fa[11]=a2.w;
        fa[12]=a3.x; fa[13]=a3.y; fa[14]=a3.z; fa[15]=a3.w;
      } else {
#pragma unroll
        for (int i = 0; i < 16; ++i) fa[i] = 0.f;
      }
    }
    const int wr = tid >> 2, kw = (tid & 3) << 3;
    if (TRANSA == 0) {
      const float* q = W + (size_t)(col0 + wr) * K + k0 + kw;
      float4 w0 = *(const float4*)q;
      float4 w1 = *(const float4*)(q + 4);
      fw[0]=w0.x; fw[1]=w0.y; fw[2]=w0.z; fw[3]=w0.w;
      fw[4]=w1.x; fw[5]=w1.y; fw[6]=w1.z; fw[7]=w1.w;
    } else {
      const float* q = W + (size_t)(col0 + wr) * K + k0 + kw;
#pragma unroll
      for (int j = 0; j < 8; ++j) fw[j] = (k0 + kw + j < K) ? q[j] : 0.f;
    }
    __syncthreads();
    if (TRANSA == 0) {
      short8 p0, p1;
#pragma unroll
      for (int j = 0; j < 8; ++j) { p0[j] = f2bf(fa[j]); p1[j] = f2bf(fa[j + 8]); }
      *(short8*)&As[ar][kh] = p0;
      *(short8*)&As[ar][kh + 8] = p1;
    } else {
#pragma unroll
      for (int i = 0; i < 16; ++i) As[tg + i][kk] = f2bf(fa[i]);
    }
    {
      short8 pw;
#pragma unroll
      for (int j = 0; j < 8; ++j) pw[j] = f2bf(fw[j]);
      *(short8*)&Ws[wr][kw] = pw;
    }
    __syncthreads();
    short8 af[4], bfr[2];
#pragma unroll
    for (int mt = 0; mt < 4; ++mt) af[mt] = *(const short8*)&As[wm * 64 + mt * 16 + fr][fkb];
#pragma unroll
    for (int nt = 0; nt < 2; ++nt) bfr[nt] = *(const short8*)&Ws[wn * 32 + nt * 16 + fr][fkb];
#pragma unroll
    for (int mt = 0; mt < 4; ++mt)
#pragma unroll
      for (int nt = 0; nt < 2; ++nt)
        acc[mt][nt] = __builtin_amdgcn_mfma_f32_16x16x32_bf16(af[mt], bfr[nt], acc[mt][nt], 0, 0, 0);
  }
#pragma unroll
  for (int nt = 0; nt < 2; ++nt) {
    const int col = col0 + wn * 32 + nt * 16 + fr;
    const float bv = bias[col];
#pragma unroll
    for (int mt = 0; mt < 4; ++mt) {
      const int rb = row0 + wm * 64 + mt * 16 + ((l >> 4) << 2);
#pragma unroll
      for (int j = 0; j < 4; ++j) {
        float v = acc[mt][nt][j] + bv;
        if (ACT == 1) v = gelu_f(v);
        C[(size_t)(rb + j) * M + col] = v;
      }
    }
  }
}

// ---------------------------------------------------------------------------
// MFMA gate (HW-verified)
// ---------------------------------------------------------------------------
template <bool PERM>
__global__ __launch_bounds__(256, 2) void mgate_k(const float* __restrict__ Y,
                                                  const float* __restrict__ R,
                                                  const float* __restrict__ W,
                                                  const float* __restrict__ bias,
                                                  float* __restrict__ Out) {
  __shared__ short As[128][40];
  __shared__ short Ws[64][40];
  const int tid = threadIdx.x;
  const int row0 = blockIdx.y << 7;
  const int col0 = blockIdx.x << 6;
  const int l = tid & 63;
  const int wid = tid >> 6;
  const int wm = wid >> 1, wn = wid & 1;
  const int fr = l & 15;
  const int fkb = (l >> 4) << 3;
  f32x4 acc[4][2];
#pragma unroll
  for (int mt = 0; mt < 4; ++mt)
#pragma unroll
    for (int nt = 0; nt < 2; ++nt) acc[mt][nt] = f32x4{0.f, 0.f, 0.f, 0.f};

  const int ar = tid >> 1, kh = (tid & 1) << 4;
  const int arow = row0 + ar;
  const int yrow = PERM ? permrow_btc_to_bct(arow) : arow;
  const int wr = tid >> 2, kw = (tid & 3) << 3;
  for (int k0 = 0; k0 < 512; k0 += 32) {
    const float* p = (k0 < 256) ? (Y + (size_t)yrow * 256 + k0 + kh)
                                : (R + (size_t)arow * 256 + (k0 - 256) + kh);
    float4 a0 = *(const float4*)p;
    float4 a1 = *(const float4*)(p + 4);
    float4 a2 = *(const float4*)(p + 8);
    float4 a3 = *(const float4*)(p + 12);
    const float* q = W + (size_t)(col0 + wr) * 512 + k0 + kw;
    float4 w0 = *(const float4*)q;
    float4 w1 = *(const float4*)(q + 4);
    __syncthreads();
    short8 p0, p1, pw;
    p0[0]=f2bf(a0.x); p0[1]=f2bf(a0.y); p0[2]=f2bf(a0.z); p0[3]=f2bf(a0.w);
    p0[4]=f2bf(a1.x); p0[5]=f2bf(a1.y); p0[6]=f2bf(a1.z); p0[7]=f2bf(a1.w);
    p1[0]=f2bf(a2.x); p1[1]=f2bf(a2.y); p1[2]=f2bf(a2.z); p1[3]=f2bf(a2.w);
    p1[4]=f2bf(a3.x); p1[5]=f2bf(a3.y); p1[6]=f2bf(a3.z); p1[7]=f2bf(a3.w);
    pw[0]=f2bf(w0.x); pw[1]=f2bf(w0.y); pw[2]=f2bf(w0.z); pw[3]=f2bf(w0.w);
    pw[4]=f2bf(w1.x); pw[5]=f2bf(w1.y); pw[6]=f2bf(w1.z); pw[7]=f2bf(w1.w);
    *(short8*)&As[ar][kh] = p0;
    *(short8*)&As[ar][kh + 8] = p1;
    *(short8*)&Ws[wr][kw] = pw;
    __syncthreads();
    short8 af[4], bfr[2];
#pragma unroll
    for (int mt = 0; mt < 4; ++mt) af[mt] = *(const short8*)&As[wm * 64 + mt * 16 + fr][fkb];
#pragma unroll
    for (int nt = 0; nt < 2; ++nt) bfr[nt] = *(const short8*)&Ws[wn * 32 + nt * 16 + fr][fkb];
#pragma unroll
    for (int mt = 0; mt < 4; ++mt)
#pragma unroll
      for (int nt = 0; nt < 2; ++nt)
        acc[mt][nt] = __builtin_amdgcn_mfma_f32_16x16x32_bf16(af[mt], bfr[nt], acc[mt][nt], 0, 0, 0);
  }
#pragma unroll
  for (int nt = 0; nt < 2; ++nt) {
    const int col = col0 + wn * 32 + nt * 16 + fr;
    const float bv = bias[col];
#pragma unroll
    for (int mt = 0; mt < 4; ++mt) {
      const int rb = row0 + wm * 64 + mt * 16 + ((l >> 4) << 2);
#pragma unroll
      for (int j = 0; j < 4; ++j) {
        const int r = rb + j;
        const int yr = PERM ? permrow_btc_to_bct(r) : r;
        float g = sigmoid_f(acc[mt][nt][j] + bv);
        float yv = Y[(size_t)yr * 256 + col];
        float rv = R[(size_t)r * 256 + col];
        Out[(size_t)r * 256 + col] = yv * g + rv * (1.f - g);
      }
    }
  }
}

// ---------------------------------------------------------------------------
// MFMA dilated conv: block per bc; C[t][hp] = gelu(sum X[ts][dch] W[hp][dch,tau] + b)
// X staged bf16 in LDS with 12 zero rows each side (dilated 'same' padding).
// Weights pre-packed in B-fragment order (wB) -> 1KB coalesced read per wave.
// ---------------------------------------------------------------------------
template <int KT>
__global__ __launch_bounds__(256) void convm_k(const short* __restrict__ xbf,
                                               const short* __restrict__ wBk,
                                               const float* __restrict__ cb,
                                               float* __restrict__ catb, int ibase) {
  const int bc = blockIdx.x;
  const int tid = threadIdx.x;
  const int l = tid & 63;
  const int wid = tid >> 6;
  const int fr = l & 15;
  const int fkb = (l >> 4) << 3;
  __shared__ short X[152][72];  // rows: 12 zero | 128 data | 12 zero; stride 144B
  // zero the pad rows once (rows 0..11 and 140..151), 36 uints per row
  for (int i = tid; i < 24 * 36; i += 256) {
    int r = i / 36, cidx = i % 36;
    int row = (r < 12) ? r : 128 + r;  // 12..23 -> 140..151
    ((unsigned*)&X[row][0])[cidx] = 0u;
  }
  f32x4 acc[3][2][2];
#pragma unroll
  for (int di = 0; di < 3; ++di)
#pragma unroll
    for (int mt = 0; mt < 2; ++mt)
#pragma unroll
      for (int nt = 0; nt < 2; ++nt) acc[di][mt][nt] = f32x4{0.f, 0.f, 0.f, 0.f};
  const short* xb = xbf + (size_t)bc * 32768;  // [128 t][256 dch]
#pragma unroll 1
  for (int dchunk = 0; dchunk < 4; ++dchunk) {
    __syncthreads();
    {
      int t = tid >> 1, dh = (tid & 1) << 5;
      const short* src = xb + t * 256 + (dchunk << 6) + dh;
#pragma unroll
      for (int s = 0; s < 4; ++s)
        *(short8*)&X[12 + t][dh + s * 8] = *(const short8*)(src + s * 8);
    }
    __syncthreads();
#pragma unroll 1
    for (int tau = 0; tau < KT; ++tau) {
#pragma unroll
      for (int sub = 0; sub < 2; ++sub) {
        const int kstep = (dchunk * KT + tau) * 2 + sub;
#pragma unroll
        for (int di = 0; di < 3; ++di) {
          const int DIL = 1 << di;
          const int PAD = ((KT - 1) << di) >> 1;
          short8 af[2], bf[2];
#pragma unroll
          for (int mt = 0; mt < 2; ++mt) {
            int t = (wid * 2 + mt) * 16 + fr;
            af[mt] = *(const short8*)&X[12 + t + tau * DIL - PAD][(sub << 5) + fkb];
          }
          const short* wp = wBk + (size_t)di * (KT * 8192) + kstep * 1024 + l * 8;
#pragma unroll
          for (int nt = 0; nt < 2; ++nt) bf[nt] = *(const short8*)(wp + nt * 512);
#pragma unroll
          for (int mt = 0; mt < 2; ++mt)
#pragma unroll
            for (int nt = 0; nt < 2; ++nt)
              acc[di][mt][nt] =
                  __builtin_amdgcn_mfma_f32_16x16x32_bf16(af[mt], bf[nt], acc[di][mt][nt], 0, 0, 0);
        }
      }
    }
  }
#pragma unroll
  for (int di = 0; di < 3; ++di)
#pragma unroll
    for (int nt = 0; nt < 2; ++nt) {
      int hp = nt * 16 + fr;
      if (hp < 28) {
        float bv = cb[di * 28 + hp];
#pragma unroll
        for (int mt = 0; mt < 2; ++mt) {
          int tb = (wid * 2 + mt) * 16 + ((l >> 4) << 2);
          float4 o;
          o.x = gelu_f(acc[di][mt][nt][0] + bv);
          o.y = gelu_f(acc[di][mt][nt][1] + bv);
          o.z = gelu_f(acc[di][mt][nt][2] + bv);
          o.w = gelu_f(acc[di][mt][nt][3] + bv);
          *(float4*)&catb[((size_t)bc * 252 + (ibase + di) * 28 + hp) * 128 + tb] = o;
        }
      }
    }
}

// x2 (fp32, rows (b,t,c)) -> xbf[bc][t][dch] bf16
__global__ __launch_bounds__(256) void xcvt_k(const float* __restrict__ In,
                                              short* __restrict__ Ob) {
  int row = (blockIdx.x << 2) + (threadIdx.x >> 6);  // (bc,t)
  int lane = threadIdx.x & 63;
  int bI = row >> 13, cI = (row >> 7) & 63, t = row & 127;
  int src = (((bI << 7) | t) << 6) | cI;
  float4 v = *(const float4*)&In[(size_t)src * 256 + (lane << 2)];
  short4v o;
  o.x = f2bf(v.x); o.y = f2bf(v.y); o.z = f2bf(v.z); o.w = f2bf(v.w);
  *(short4v*)&Ob[(size_t)row * 256 + (lane << 2)] = o;
}

// conv weights -> bf16 B-fragment layout wB[branch][kstep][nt][lane][8]
// k order: dchunk(4) x tau(KT) x dch(64); branch = (ki, di)
__global__ void wtransB_k(const float* __restrict__ w3, const float* __restrict__ w5,
                          const float* __restrict__ w7, short* __restrict__ wB) {
  int ib = blockIdx.y;  // 0..8
  int ki = ib / 3, di = ib % 3;
  int KT = (ki == 0) ? 3 : (ki == 1) ? 5 : 7;
  int nelem = KT * 8192;
  int e = blockIdx.x * 256 + threadIdx.x;
  if (e >= nelem) return;
  int base = ((ki == 0) ? 0 : (ki == 1) ? 73728 : 196608) + di * nelem;
  int kstep = e >> 10, rem = e & 1023;
  int nt = rem >> 9, le = rem & 511;
  int l = le >> 3, j = le & 7;
  int hp = nt * 16 + (l & 15);
  int kk = (kstep << 5) + ((l >> 4) << 3) + j;
  int KTc = KT << 6;
  int dchunk = kk / KTc, r2 = kk % KTc;
  int tau = r2 >> 6, dch = (dchunk << 6) + (r2 & 63);
  const float* src = (ki == 0) ? w3 : (ki == 1) ? w5 : w7;
  float v = (hp < 28) ? src[(((size_t)di * 28 + hp) * 256 + dch) * KT + tau] : 0.f;
  wB[base + e] = f2bf(v);
}

// ---------------------------------------------------------------------------
// Attention (online softmax), one wave-lane per query row. L=64 (bias) or 128.
// ---------------------------------------------------------------------------
template <int L, bool HASB>
__global__ __launch_bounds__(L) void attn_k(const float* __restrict__ qkv,
                                            const float* __restrict__ bmat,
                                            float* __restrict__ Out) {
  __shared__ float Ks[L][34];
  __shared__ float Vs[L][34];
  __shared__ float Bs[HASB ? 64 * 65 : 1];
  const int s = blockIdx.x, h = blockIdx.y, l = threadIdx.x;
  const float* rowp = qkv + ((size_t)s * L + l) * 768 + h * 32;
  float q[32];
#pragma unroll
  for (int e = 0; e < 32; e += 4) {
    float4 t4 = *(const float4*)(rowp + e);
    q[e] = t4.x; q[e + 1] = t4.y; q[e + 2] = t4.z; q[e + 3] = t4.w;
    float4 k4 = *(const float4*)(rowp + 256 + e);
    Ks[l][e] = k4.x; Ks[l][e + 1] = k4.y; Ks[l][e + 2] = k4.z; Ks[l][e + 3] = k4.w;
    float4 v4 = *(const float4*)(rowp + 512 + e);
    Vs[l][e] = v4.x; Vs[l][e + 1] = v4.y; Vs[l][e + 2] = v4.z; Vs[l][e + 3] = v4.w;
  }
  if (HASB) {
#pragma unroll 1
    for (int j = 0; j < 64; ++j) Bs[l * 65 + j] = bmat[l * 64 + j];
  }
  __syncthreads();
  float m = -3.0e38f, den = 0.f;
  float acc[32];
#pragma unroll
  for (int e = 0; e < 32; ++e) acc[e] = 0.f;
  for (int kk = 0; kk < L; ++kk) {
    float sd = 0.f;
#pragma unroll
    for (int e = 0; e < 32; e += 2) {
      float2 kv = *(const float2*)&Ks[kk][e];
      sd = fmaf(q[e], kv.x, sd);
      sd = fmaf(q[e + 1], kv.y, sd);
    }
    float sc = sd * 0.17677669529663687f;
    if (HASB) sc += Bs[l * 65 + kk];
    float mn = fmaxf(m, sc);
    float corr = __expf(m - mn);
    float p = __expf(sc - mn);
    den = den * corr + p;
#pragma unroll
    for (int e = 0; e < 32; e += 2) {
      float2 vv = *(const float2*)&Vs[kk][e];
      acc[e] = acc[e] * corr + p * vv.x;
      acc[e + 1] = acc[e + 1] * corr + p * vv.y;
    }
    m = mn;
  }
  float inv = 1.f / den;
  float* op = Out + ((size_t)s * L + l) * 256 + h * 32;
#pragma unroll
  for (int e = 0; e < 32; e += 4) {
    float4 o;
    o.x = acc[e] * inv; o.y = acc[e + 1] * inv; o.z = acc[e + 2] * inv; o.w = acc[e + 3] * inv;
    *(float4*)(op + e) = o;
  }
}

// ---------------------------------------------------------------------------
// LayerNorm over last dim (256), one wave per row. Modes as before.
// ---------------------------------------------------------------------------
template <int MODE>
__global__ __launch_bounds__(256) void ln_k(const float* __restrict__ A,
                                            const float* __restrict__ Res,
                                            const float* __restrict__ w,
                                            const float* __restrict__ b,
                                            float* __restrict__ Out) {
  int row = (blockIdx.x << 2) + (threadIdx.x >> 6);
  int lane = threadIdx.x & 63;
  int j0 = lane << 2;
  float4 v = *(const float4*)&A[(size_t)row * 256 + j0];
  if (MODE == 0) {
    float4 r4 = *(const float4*)&Res[(size_t)row * 256 + j0];
    v.x += r4.x; v.y += r4.y; v.z += r4.z; v.w += r4.w;
  }
  float mean = wred_sum(v.x + v.y + v.z + v.w) * (1.f / 256.f);
  float dx = v.x - mean, dy = v.y - mean, dz = v.z - mean, dw = v.w - mean;
  float var = wred_sum(dx * dx + dy * dy + dz * dz + dw * dw) * (1.f / 256.f);
  float rstd = rsqrtf(var + LN_EPS);
  float4 wv = *(const float4*)&w[j0];
  float4 bv = *(const float4*)&b[j0];
  float4 o;
  o.x = dx * rstd * wv.x + bv.x;
  o.y = dy * rstd * wv.y + bv.y;
  o.z = dz * rstd * wv.z + bv.z;
  o.w = dw * rstd * wv.w + bv.w;
  if (MODE == 2) {
    int bc = row >> 7, t = row & 127;
    int pr = ((((bc >> 6) << 7) | t) << 6) | (bc & 63);
    float4 rv = *(const float4*)&Res[(size_t)pr * 256 + j0];
    o.x = rv.x + 0.5f * o.x;
    o.y = rv.y + 0.5f * o.y;
    o.z = rv.z + 0.5f * o.z;
    o.w = rv.w + 0.5f * o.w;
    *(float4*)&Out[(size_t)pr * 256 + j0] = o;
  } else {
    *(float4*)&Out[(size_t)row * 256 + j0] = o;
  }
}

// ---------------------------------------------------------------------------
// GroupNorm in place on cat[bc, 252, 128]
// ---------------------------------------------------------------------------
__global__ __launch_bounds__(256) void gn_k(float* __restrict__ catb,
                                            const float* __restrict__ gw,
                                            const float* __restrict__ gb) {
  int bc = blockIdx.x, ib = blockIdx.y;
  int grp = threadIdx.x >> 6;
  int lane = threadIdx.x & 63;
  float* base = catb + ((size_t)bc * 252 + ib * 28 + grp * 7) * 128;
  float vals[14];
  float s = 0.f, s2 = 0.f;
#pragma unroll
  for (int j = 0; j < 14; ++j) {
    float x = base[lane + (j << 6)];
    vals[j] = x;
    s += x;
    s2 = fmaf(x, x, s2);
  }
  s = wred_sum(s);
  s2 = wred_sum(s2);
  float mean = s * (1.f / 896.f);
  float var = s2 * (1.f / 896.f) - mean * mean;
  float rstd = rsqrtf(var + LN_EPS);
#pragma unroll
  for (int j = 0; j < 14; ++j) {
    int e = lane + (j << 6);
    int hp = grp * 7 + (e >> 7);
    base[e] = (vals[j] - mean) * rstd * gw[ib * 28 + hp] + gb[ib * 28 + hp];
  }
}

// Transpose (b,t,c,d) -> (b,c,t,d)
__global__ __launch_bounds__(256) void transp_k(const float* __restrict__ In,
                                                float* __restrict__ Ot) {
  int row = (blockIdx.x << 2) + (threadIdx.x >> 6);
  int lane = threadIdx.x & 63;
  int bI = row >> 13, cI = (row >> 7) & 63, t = row & 127;
  int src = ((((bI << 7) | t) << 6) | cI);
  float4 v = *(const float4*)&In[(size_t)src * 256 + (lane << 2)];
  *(float4*)&Ot[(size_t)row * 256 + (lane << 2)] = v;
}

// Mean over heads of relpos -> bias[64*64]
__global__ void biasmean_k(const float* __restrict__ relpos, float* __restrict__ bout) {
  int idx = blockIdx.x * 256 + threadIdx.x;
  if (idx >= 4096) return;
  float sv = 0.f;
#pragma unroll
  for (int h = 0; h < 8; ++h) sv += relpos[h * 4096 + idx];
  bout[idx] = sv * 0.125f;
}

// ---------------------------------------------------------------------------
extern "C" void kernel_launch(void* const* d_in, const int* in_sizes, int n_in,
                              void* d_out, int out_size, void* d_ws, size_t ws_size,
                              hipStream_t stream) {
  const float* x = (const float*)d_in[0];
  const float* sa_wqkv = (const float*)d_in[1];
  const float* sa_bqkv = (const float*)d_in[2];
  const float* sa_wout = (const float*)d_in[3];
  const float* sa_bout = (const float*)d_in[4];
  const float* sa_relpos = (const float*)d_in[5];
  const float* sa_ln_w = (const float*)d_in[6];
  const float* sa_ln_b = (const float*)d_in[7];
  const float* ta_wqkv = (const float*)d_in[8];
  const float* ta_bqkv = (const float*)d_in[9];
  const float* ta_wout = (const float*)d_in[10];
  const float* ta_bout = (const float*)d_in[11];
  const float* ta_ln_w = (const float*)d_in[12];
  const float* ta_ln_b = (const float*)d_in[13];
  const float* cw3 = (const float*)d_in[14];
  const float* cw5 = (const float*)d_in[15];
  const float* cw7 = (const float*)d_in[16];
  const float* cb3 = (const float*)d_in[17];
  const float* cb5 = (const float*)d_in[18];
  const float* cb7 = (const float*)d_in[19];
  const float* gn_w = (const float*)d_in[20];
  const float* gn_b = (const float*)d_in[21];
  const float* proj_w = (const float*)d_in[22];
  const float* proj_b = (const float*)d_in[23];
  const float* conv_ln_w = (const float*)d_in[24];
  const float* conv_ln_b = (const float*)d_in[25];
  const float* ff_w1 = (const float*)d_in[26];
  const float* ff_b1 = (const float*)d_in[27];
  const float* ff_w2 = (const float*)d_in[28];
  const float* ff_b2 = (const float*)d_in[29];
  const float* ff_ln_w = (const float*)d_in[30];
  const float* ff_ln_b = (const float*)d_in[31];
  const float* g1_w = (const float*)d_in[32];
  const float* g1_b = (const float*)d_in[33];
  const float* g2_w = (const float*)d_in[34];
  const float* g2_b = (const float*)d_in[35];
  const float* g3_w = (const float*)d_in[36];
  const float* g3_b = (const float*)d_in[37];
  float* O = (float*)d_out;  // scratch: xt, then x2, then final output

  // --- adaptive workspace layout ---
  // A, B full buffers; xbf (bf16 x2 copy) aliases the first half of B
  // (B is dead between mgate<true> and convproj). wB = packed conv weights.
  const size_t FULL = 16777216;  // 65536*256
  size_t avail_f = ws_size / sizeof(float);
  const size_t fixed_f = 2 * FULL + 4096 + 184320;
  size_t rem = (avail_f > fixed_f) ? (avail_f - fixed_f) : 0;
  int Rc = 16384;
  while ((size_t)Rc * 1280 > rem && Rc > 128) Rc >>= 1;
  const int nc = 65536 / Rc;

  float* ws = (float*)d_ws;
  float* A = ws;
  float* B = A + FULL;
  float* S1 = B + FULL;
  float* S2 = S1 + (size_t)Rc * 1024;
  float* biasb = S2 + (size_t)Rc * 256;
  short* wB = (short*)(biasb + 4096);  // 368640 shorts = 184320 float slots
  short* xbf = (short*)B;              // 16.7M shorts = first half of B
  const size_t CHD = (size_t)Rc * 256;

  // --- prep ---
  biasmean_k<<<16, 256, 0, stream>>>(sa_relpos, biasb);
  wtransB_k<<<dim3(224, 9), 256, 0, stream>>>(cw3, cw5, cw7, wB);

  // --- spatial attention ---
  for (int c = 0; c < nc; ++c) {
    mgemm_k<0, 0><<<dim3(12, Rc / 128), 256, 0, stream>>>(x + c * CHD, sa_wqkv, sa_bqkv, S1, 256, 768);
    attn_k<64, true><<<dim3(Rc / 64, 8), 64, 0, stream>>>(S1, biasb, S2);
    mgemm_k<0, 0><<<dim3(4, Rc / 128), 256, 0, stream>>>(S2, sa_wout, sa_bout, A + c * CHD, 256, 256);
  }
  ln_k<0><<<16384, 256, 0, stream>>>(A, x, sa_ln_w, sa_ln_b, A);          // A = so
  mgate_k<false><<<dim3(4, 512), 256, 0, stream>>>(A, x, g1_w, g1_b, B);  // B = x1

  // --- temporal attention (xt staged in d_out) ---
  transp_k<<<16384, 256, 0, stream>>>(B, O);                              // O = xt
  for (int c = 0; c < nc; ++c) {
    mgemm_k<0, 0><<<dim3(12, Rc / 128), 256, 0, stream>>>(O + c * CHD, ta_wqkv, ta_bqkv, S1, 256, 768);
    attn_k<128, false><<<dim3(Rc / 128, 8), 128, 0, stream>>>(S1, nullptr, S2);
    mgemm_k<0, 0><<<dim3(4, Rc / 128), 256, 0, stream>>>(S2, ta_wout, ta_bout, A + c * CHD, 256, 256);
  }
  ln_k<0><<<16384, 256, 0, stream>>>(A, O, ta_ln_w, ta_ln_b, A);          // A = to
  mgate_k<true><<<dim3(4, 512), 256, 0, stream>>>(A, B, g2_w, g2_b, O);   // O = x2 (B dead)

  // --- multi-scale conv (MFMA) ---
  xcvt_k<<<16384, 256, 0, stream>>>(O, xbf);                              // xbf = bf16 x2
  convm_k<3><<<512, 256, 0, stream>>>(xbf, wB, cb3, A, 0);
  convm_k<5><<<512, 256, 0, stream>>>(xbf, wB + 73728, cb5, A, 3);
  convm_k<7><<<512, 256, 0, stream>>>(xbf, wB + 196608, cb7, A, 6);       // A = cat
  gn_k<<<dim3(512, 9), 256, 0, stream>>>(A, gn_w, gn_b);
  mgemm_k<0, 1><<<dim3(4, 512), 256, 0, stream>>>(A, proj_w, proj_b, B, 252, 256);  // B = co
  ln_k<2><<<16384, 256, 0, stream>>>(B, O, conv_ln_w, conv_ln_b, A);      // A = x3

  // --- FFN + final gate, chunked; writes d_out ---
  for (int c = 0; c < nc; ++c) {
    mgemm_k<1, 0><<<dim3(16, Rc / 128), 256, 0, stream>>>(A + c * CHD, ff_w1, ff_b1, S1, 256, 1024);
    mgemm_k<0, 0><<<dim3(4, Rc / 128), 256, 0, stream>>>(S1, ff_w2, ff_b2, S2, 1024, 256);
    ln_k<1><<<Rc / 4, 256, 0, stream>>>(S2, nullptr, ff_ln_w, ff_ln_b, S2);
    mgate_k<false><<<dim3(4, Rc / 128), 256, 0, stream>>>(S2, A + c * CHD, g3_w, g3_b, O + c * CHD);
  }
}